// Round 3
// baseline (4552.224 us; speedup 1.0000x reference)
//
#include <hip/hip_runtime.h>

// ResidualVQ on MI355X — fused single-kernel, fp32 outputs.
// x [8,2048,512] f32, codebooks [8,1024,512] f32.
// d_out (float*): quantized_out [8*2048*512], indices [8*2048*8] (as float),
// expired [8], losses [8]  — concatenated flat in return order.
//
// No d_ws use at all. Losses accumulate via atomicAdd into d_out tail.
// All 8 stages in one kernel; residual lives in LDS [D=512][BM=64] k-major;
// quantized_out = x - residual_final; loss_q = mean(r_new^2).

constexpr int DD = 512;
constexpr int KK = 1024;
constexpr int QQ = 8;
constexpr int NROWS = 16384;      // B*S
constexpr int BM = 64;
constexpr int NBLK = NROWS / BM;  // 256
constexpr int NT = 512;           // 8 waves

__global__ void tail_init(float* __restrict__ tail) {
  // tail = out + 8519680: expired[8] then losses[8]; zero both.
  if (threadIdx.x < 16) tail[threadIdx.x] = 0.0f;
}

__global__ void tail_fin(float* __restrict__ loss) {
  if (threadIdx.x < QQ) loss[threadIdx.x] *= (1.0f / 8388608.0f);
}

__global__ __launch_bounds__(NT, 1) void rvq_fused(
    const float* __restrict__ x,
    const float* __restrict__ cb,
    float* __restrict__ outQ,      // fp32 quantized
    float* __restrict__ outIdx,    // fp32 indices
    float* __restrict__ outLoss)   // fp32 raw loss sums (pre-zeroed)
{
  extern __shared__ float smem[];
  float* ldsA = smem;                    // [DD][BM] k-major residual 32768 f
  float* c2s  = smem + DD * BM;          // 1024 f  per-stage ||c||^2
  float* r2s  = c2s + KK;                // 64 f    per-row ||r||^2
  float* bD   = r2s + BM;                // 512 f
  int*   bI   = reinterpret_cast<int*>(bD + NT);   // 512 i
  int*   fI   = bI + NT;                 // 64 i

  const int tid  = threadIdx.x;
  const int lane = tid & 63;
  const int row  = tid >> 3;             // 0..63
  const int seg  = tid & 7;              // 0..7 (64-dim chunks)
  const int rowBase = blockIdx.x * BM;
  const size_t gRow = (size_t)(rowBase + row) * DD + seg * 64;
  const float4* xp = reinterpret_cast<const float4*>(x + gRow);

  // ---- Prologue: residual = x -> LDS k-major; per-row r2 ----
  {
    float s = 0.f;
    #pragma unroll
    for (int j = 0; j < 16; ++j) {
      float4 v = xp[j];
      const int d0 = seg * 64 + j * 4;
      ldsA[(d0+0)*BM + row] = v.x;
      ldsA[(d0+1)*BM + row] = v.y;
      ldsA[(d0+2)*BM + row] = v.z;
      ldsA[(d0+3)*BM + row] = v.w;
      s += v.x*v.x; s += v.y*v.y; s += v.z*v.z; s += v.w*v.w;
    }
    s += __shfl_xor(s, 1, 64);
    s += __shfl_xor(s, 2, 64);
    s += __shfl_xor(s, 4, 64);   // lanes 8r..8r+7 hold row r
    if (seg == 0) r2s[row] = s;
  }
  __syncthreads();

  for (int q = 0; q < QQ; ++q) {
    const float* cbq = cb + (size_t)q * KK * DD;

    // ---- c2 for this stage (per-block, into LDS) ----
    for (int c = tid; c < KK; c += NT) {          // 2 codes per thread
      const float4* p = reinterpret_cast<const float4*>(cbq + (size_t)c * DD);
      float t0 = 0.f;
      #pragma unroll 8
      for (int m = 0; m < 128; ++m) {
        float4 v = p[m];
        t0 += v.x*v.x; t0 += v.y*v.y; t0 += v.z*v.z; t0 += v.w*v.w;
      }
      c2s[c] = t0;
    }
    __syncthreads();

    // ---- Fused GEMM + argmin: wave wv owns cols [128*wv, 128*wv+128) ----
    {
      const int wv = __builtin_amdgcn_readfirstlane(tid >> 6);
      const float r2v = r2s[lane];          // lane == tracked row
      float bestD = 3.0e38f;
      int bestI = 0;
      const int colBase = wv * 128;
      for (int cbt = 0; cbt < 8; ++cbt) {
        float acc[16];
        #pragma unroll
        for (int c = 0; c < 16; ++c) acc[c] = 0.f;
        const float* bbase = cbq + (size_t)(colBase + cbt * 16) * DD; // uniform
        for (int kb = 0; kb < 64; ++kb) {
          float a[8];
          #pragma unroll
          for (int i = 0; i < 8; ++i) a[i] = ldsA[(kb*8 + i)*BM + lane];
          #pragma unroll
          for (int c = 0; c < 16; ++c) {
            const float* bp = bbase + c * DD + kb * 8;  // uniform -> s_load
            #pragma unroll
            for (int i = 0; i < 8; ++i) acc[c] = fmaf(a[i], bp[i], acc[c]);
          }
        }
        #pragma unroll
        for (int c = 0; c < 16; ++c) {
          const int col = colBase + cbt * 16 + c;
          const float dsq = (r2v - 2.0f * acc[c]) + c2s[col];  // np op order
          if (dsq < bestD) { bestD = dsq; bestI = col; }       // first-idx tie
        }
      }
      bD[tid] = bestD;
      bI[tid] = bestI;
    }
    __syncthreads();

    // ---- Cross-wave argmin (ascending col ranges, strict <) + idx out ----
    if (tid < BM) {
      float best = bD[tid];
      int bi = bI[tid];
      #pragma unroll
      for (int w = 1; w < 8; ++w) {
        const float dw = bD[w*64 + tid];
        if (dw < best) { best = dw; bi = bI[w*64 + tid]; }
      }
      fI[tid] = bi;
      outIdx[(size_t)(rowBase + tid) * QQ + q] = (float)bi;
    }
    __syncthreads();

    // ---- Update: r -= codebook[idx]; new per-row r2 ----
    {
      const int myI = fI[row];
      const float4* qp = reinterpret_cast<const float4*>(
          cbq + (size_t)myI * DD + seg * 64);
      float s2 = 0.f;
      #pragma unroll
      for (int j = 0; j < 16; ++j) {
        float4 qv = qp[j];
        const int d0 = seg * 64 + j * 4;
        float r0 = ldsA[(d0+0)*BM + row] - qv.x;
        float r1 = ldsA[(d0+1)*BM + row] - qv.y;
        float r2_ = ldsA[(d0+2)*BM + row] - qv.z;
        float r3 = ldsA[(d0+3)*BM + row] - qv.w;
        ldsA[(d0+0)*BM + row] = r0;
        ldsA[(d0+1)*BM + row] = r1;
        ldsA[(d0+2)*BM + row] = r2_;
        ldsA[(d0+3)*BM + row] = r3;
        s2 += r0*r0; s2 += r1*r1; s2 += r2_*r2_; s2 += r3*r3;
      }
      s2 += __shfl_xor(s2, 1, 64);
      s2 += __shfl_xor(s2, 2, 64);
      s2 += __shfl_xor(s2, 4, 64);
      if (seg == 0) r2s[row] = s2;
    }
    __syncthreads();

    // ---- loss_q += sum(r_new^2) for this block ----
    if (tid < 64) {
      float v = r2s[tid];
      v += __shfl_xor(v, 1, 64);
      v += __shfl_xor(v, 2, 64);
      v += __shfl_xor(v, 4, 64);
      v += __shfl_xor(v, 8, 64);
      v += __shfl_xor(v, 16, 64);
      v += __shfl_xor(v, 32, 64);
      if (tid == 0) atomicAdd(outLoss + q, v);
    }
    // c2s/bD writes of next stage are fenced by the sync after c2 compute.
  }

  // ---- Epilogue: quantized_out = x - residual_final (fp32) ----
  {
    float4* op = reinterpret_cast<float4*>(outQ + gRow);
    #pragma unroll
    for (int j = 0; j < 16; ++j) {
      float4 xv = xp[j];
      const int d0 = seg * 64 + j * 4;
      float4 o;
      o.x = xv.x - ldsA[(d0+0)*BM + row];
      o.y = xv.y - ldsA[(d0+1)*BM + row];
      o.z = xv.z - ldsA[(d0+2)*BM + row];
      o.w = xv.w - ldsA[(d0+3)*BM + row];
      op[j] = o;
    }
  }
}

extern "C" void kernel_launch(void* const* d_in, const int* in_sizes, int n_in,
                              void* d_out, int out_size, void* d_ws, size_t ws_size,
                              hipStream_t stream) {
  const float* x  = (const float*)d_in[0];
  const float* cb = (const float*)d_in[1];

  float* out     = (float*)d_out;
  float* outQ    = out;                              // [0, 8388608)
  float* outIdx  = out + (size_t)NROWS * DD;         // [8388608, 8519680)
  float* tail    = outIdx + (size_t)NROWS * QQ;      // expired[8], losses[8]
  float* outLoss = tail + QQ;

  const size_t shmem = (size_t)(DD*BM + KK + BM + NT + NT + BM) * 4;  // 139776 B
  (void)hipFuncSetAttribute((const void*)rvq_fused,
                            hipFuncAttributeMaxDynamicSharedMemorySize,
                            (int)shmem);

  tail_init<<<1, 64, 0, stream>>>(tail);
  rvq_fused<<<NBLK, NT, shmem, stream>>>(x, cb, outQ, outIdx, outLoss);
  tail_fin<<<1, 64, 0, stream>>>(outLoss);
}

// Round 5
// 797.266 us; speedup vs baseline: 5.7098x; 5.7098x over previous
//
#include <hip/hip_runtime.h>

// ResidualVQ on MI355X — split-fp16 MFMA design.
// x [8,2048,512] f32, codebooks [8,1024,512] f32.
// d_out (float*): quantized [8388608], indices [131072], expired [8], losses [8].
//
// r = h + m/2048 (h=fp16(r), m=fp16((r-h)*2048)): dot = hH + (hM + mH)/2048.
// Dropped mM term ~2e-6 << argmin gaps. Distances compared as c2 - 2*dot
// (r2 is per-row constant -> argmin-invariant). Residual stored as (h,m)
// fp16 pairs in LDS (XOR-swizzled). B-splits (H,M) + c2 precomputed into the
// outQ region (scratch until recon kernel overwrites it with the real output).
//
// Round-5 fix: c2s staging covered [0,768) and left [768,1024) as garbage
// (tid+256 instead of tid+512) -> cols 768..1023 had wrong c2 -> argmin
// flips (indices absmax 1023). Surgical 2-line fix, rest identical.

typedef _Float16 half8 __attribute__((ext_vector_type(8)));
typedef float f32x4 __attribute__((ext_vector_type(4)));

constexpr int DD = 512;
constexpr int KK = 1024;
constexpr int QQ = 8;
constexpr int NROWS = 16384;
constexpr int BM = 64;
constexpr int NBLK = NROWS / BM;   // 256
constexpr int NT = 512;            // 8 waves
constexpr float INV2048 = 1.0f / 2048.0f;

__global__ void tail_init(float* __restrict__ tail) {
  if (threadIdx.x < 16) tail[threadIdx.x] = 0.0f;
}
__global__ void tail_fin(float* __restrict__ loss) {
  if (threadIdx.x < QQ) loss[threadIdx.x] *= (1.0f / 8388608.0f);
}

// ---- B-split + c2 precompute: one wave per code ----
__global__ __launch_bounds__(256) void prep_kernel(
    const float* __restrict__ cb, _Float16* __restrict__ Hs,
    _Float16* __restrict__ Ms, float* __restrict__ c2g) {
  const int code = blockIdx.x * 4 + (threadIdx.x >> 6);   // 0..8191
  const int lane = threadIdx.x & 63;
  const float4* p = reinterpret_cast<const float4*>(cb + (size_t)code * DD + lane * 8);
  float4 a = p[0], b = p[1];
  float v[8] = {a.x,a.y,a.z,a.w,b.x,b.y,b.z,b.w};
  half8 h, m;
  float s = 0.f;
  #pragma unroll
  for (int i = 0; i < 8; ++i) {
    _Float16 hi = (_Float16)v[i];
    h[i] = hi;
    m[i] = (_Float16)((v[i] - (float)hi) * 2048.0f);
    s += v[i] * v[i];
  }
  const size_t off = (size_t)code * DD + lane * 8;
  *reinterpret_cast<half8*>(Hs + off) = h;
  *reinterpret_cast<half8*>(Ms + off) = m;
  #pragma unroll
  for (int o = 32; o > 0; o >>= 1) s += __shfl_down(s, o, 64);
  if (lane == 0) c2g[code] = s;
}

// ---- Main fused 8-stage kernel: writes indices + loss only ----
__global__ __launch_bounds__(NT, 2) void rvq_mfma(
    const float* __restrict__ x, const float* __restrict__ cb,
    const _Float16* __restrict__ Hs, const _Float16* __restrict__ Ms,
    const float* __restrict__ c2g, float* __restrict__ outIdx,
    float* __restrict__ outLoss) {
  extern __shared__ char smem[];
  // ash: [2 splits][64 rows][512 k] fp16, XOR-swizzled: 131072 B
  char* ash = smem;
  float* c2s = reinterpret_cast<float*>(smem + 131072);   // 1024 f
  float* bD  = c2s + KK;                                  // 512 f
  int*   bI  = reinterpret_cast<int*>(bD + NT);           // 512 i
  int*   fI  = bI + NT;                                   // 64 i

  const int tid  = threadIdx.x;
  const int lane = tid & 63;
  const int wv   = tid >> 6;
  const int rowBase = blockIdx.x * BM;
  const int row = tid >> 3;        // 0..63 (ownership for staging/update)
  const int seg = tid & 7;         // 64-k chunk

  auto aAddr = [&](int split, int r, int k) -> char* {
    return ash + split * 65536 + (((r << 10) + (k << 1)) ^ ((r & 7) << 4));
  };

  // ---- Prologue: residual = x -> (h,m) fp16 splits in LDS ----
  {
    const float4* xp = reinterpret_cast<const float4*>(
        x + (size_t)(rowBase + row) * DD + seg * 64);
    #pragma unroll
    for (int g = 0; g < 8; ++g) {
      float4 a = xp[2*g], b = xp[2*g+1];
      float v[8] = {a.x,a.y,a.z,a.w,b.x,b.y,b.z,b.w};
      half8 h, m;
      #pragma unroll
      for (int i = 0; i < 8; ++i) {
        _Float16 hi = (_Float16)v[i];
        h[i] = hi;
        m[i] = (_Float16)((v[i] - (float)hi) * 2048.0f);
      }
      const int k0 = seg * 64 + g * 8;
      *reinterpret_cast<half8*>(aAddr(0, row, k0)) = h;
      *reinterpret_cast<half8*>(aAddr(1, row, k0)) = m;
    }
  }

  for (int q = 0; q < QQ; ++q) {
    // stage c2 -> LDS (NT=512 threads cover KK=1024 in two strides)
    c2s[tid]       = c2g[q * KK + tid];
    c2s[tid + 512] = c2g[q * KK + tid + 512];
    __syncthreads();

    // ---- GEMM + per-lane argmin. Wave owns cols [wv*128, wv*128+128). ----
    float bestD[16];
    int   bestC[16];
    #pragma unroll
    for (int s = 0; s < 16; ++s) { bestD[s] = 3.0e38f; bestC[s] = 0; }

    #pragma unroll 1
    for (int pass = 0; pass < 2; ++pass) {
      f32x4 acc1[4][4], acc2[4][4];
      #pragma unroll
      for (int ct = 0; ct < 4; ++ct)
        #pragma unroll
        for (int mt = 0; mt < 4; ++mt) {
          acc1[ct][mt] = (f32x4){0.f,0.f,0.f,0.f};
          acc2[ct][mt] = (f32x4){0.f,0.f,0.f,0.f};
        }
      #pragma unroll 1
      for (int kc = 0; kc < 16; ++kc) {
        const int k0 = kc * 32 + (lane >> 4) * 8;
        half8 ah[4], am[4];
        #pragma unroll
        for (int mt = 0; mt < 4; ++mt) {
          const int r = mt * 16 + (lane & 15);
          ah[mt] = *reinterpret_cast<const half8*>(aAddr(0, r, k0));
          am[mt] = *reinterpret_cast<const half8*>(aAddr(1, r, k0));
        }
        #pragma unroll
        for (int ct = 0; ct < 4; ++ct) {
          const int col = wv * 128 + pass * 64 + ct * 16 + (lane & 15);
          const size_t boff = (size_t)(q * KK + col) * DD + k0;
          half8 bh = *reinterpret_cast<const half8*>(Hs + boff);
          half8 bm = *reinterpret_cast<const half8*>(Ms + boff);
          #pragma unroll
          for (int mt = 0; mt < 4; ++mt) {
            acc1[ct][mt] = __builtin_amdgcn_mfma_f32_16x16x32_f16(ah[mt], bh, acc1[ct][mt], 0, 0, 0);
            acc2[ct][mt] = __builtin_amdgcn_mfma_f32_16x16x32_f16(ah[mt], bm, acc2[ct][mt], 0, 0, 0);
            acc2[ct][mt] = __builtin_amdgcn_mfma_f32_16x16x32_f16(am[mt], bh, acc2[ct][mt], 0, 0, 0);
          }
        }
      }
      // distances for this pass (cols ascending: pass-major, ct-minor)
      #pragma unroll
      for (int ct = 0; ct < 4; ++ct) {
        const int col = wv * 128 + pass * 64 + ct * 16 + (lane & 15);
        const float c2v = c2s[col];
        #pragma unroll
        for (int mt = 0; mt < 4; ++mt) {
          #pragma unroll
          for (int r = 0; r < 4; ++r) {
            const float dot = acc1[ct][mt][r] + INV2048 * acc2[ct][mt][r];
            const float d = c2v - 2.0f * dot;
            const int s = mt * 4 + r;
            if (d < bestD[s]) { bestD[s] = d; bestC[s] = col; }
          }
        }
      }
    }
    // cross-lane argmin within 16-lane col groups (tie -> lower col)
    #pragma unroll
    for (int s = 0; s < 16; ++s) {
      #pragma unroll
      for (int xm = 1; xm <= 8; xm <<= 1) {
        const float od = __shfl_xor(bestD[s], xm, 64);
        const int   oc = __shfl_xor(bestC[s], xm, 64);
        if (od < bestD[s] || (od == bestD[s] && oc < bestC[s])) {
          bestD[s] = od; bestC[s] = oc;
        }
      }
    }
    if ((lane & 15) == 0) {
      #pragma unroll
      for (int s = 0; s < 16; ++s) {
        const int rl = (s >> 2) * 16 + (lane >> 4) * 4 + (s & 3);
        bD[wv * 64 + rl] = bestD[s];
        bI[wv * 64 + rl] = bestC[s];
      }
    }
    __syncthreads();
    // cross-wave (ascending col ranges, strict < keeps first occurrence)
    if (tid < BM) {
      float best = bD[tid];
      int bi = bI[tid];
      #pragma unroll
      for (int w = 1; w < 8; ++w) {
        const float dw = bD[w * 64 + tid];
        if (dw < best) { best = dw; bi = bI[w * 64 + tid]; }
      }
      fI[tid] = bi;
      outIdx[(size_t)(rowBase + tid) * QQ + q] = (float)bi;
    }
    __syncthreads();

    // ---- Update: r -= codebook[idx]; re-split; loss += r_new^2 ----
    {
      const int myI = fI[row];
      const float4* cp = reinterpret_cast<const float4*>(
          cb + ((size_t)q * KK + myI) * DD + seg * 64);
      float s2 = 0.f;
      #pragma unroll
      for (int g = 0; g < 8; ++g) {
        const int k0 = seg * 64 + g * 8;
        half8 h = *reinterpret_cast<const half8*>(aAddr(0, row, k0));
        half8 m = *reinterpret_cast<const half8*>(aAddr(1, row, k0));
        float4 ca = cp[2*g], cb4 = cp[2*g+1];
        float c[8] = {ca.x,ca.y,ca.z,ca.w,cb4.x,cb4.y,cb4.z,cb4.w};
        half8 nh, nm;
        #pragma unroll
        for (int i = 0; i < 8; ++i) {
          const float r0 = (float)h[i] + (float)m[i] * INV2048;
          const float rn = r0 - c[i];
          s2 += rn * rn;
          _Float16 hi = (_Float16)rn;
          nh[i] = hi;
          nm[i] = (_Float16)((rn - (float)hi) * 2048.0f);
        }
        *reinterpret_cast<half8*>(aAddr(0, row, k0)) = nh;
        *reinterpret_cast<half8*>(aAddr(1, row, k0)) = nm;
      }
      #pragma unroll
      for (int o = 32; o > 0; o >>= 1) s2 += __shfl_down(s2, o, 64);
      if (lane == 0) atomicAdd(outLoss + q, s2);
    }
    __syncthreads();
  }
}

// ---- Reconstruction: quantized_out = sum_q codebook[q][idx_q] (np order) ----
__global__ __launch_bounds__(256) void recon_kernel(
    const float* __restrict__ cb, const float* __restrict__ outIdx,
    float* __restrict__ outQ) {
  const int row = blockIdx.x * 4 + (threadIdx.x >> 6);
  const int lane = threadIdx.x & 63;
  const int d0 = lane * 8;
  float o[8] = {0,0,0,0,0,0,0,0};
  #pragma unroll
  for (int q = 0; q < QQ; ++q) {
    const int idx = (int)outIdx[(size_t)row * QQ + q];
    const float4* cp = reinterpret_cast<const float4*>(
        cb + ((size_t)q * KK + idx) * DD + d0);
    float4 a = cp[0], b = cp[1];
    o[0] += a.x; o[1] += a.y; o[2] += a.z; o[3] += a.w;
    o[4] += b.x; o[5] += b.y; o[6] += b.z; o[7] += b.w;
  }
  float4* op = reinterpret_cast<float4*>(outQ + (size_t)row * DD + d0);
  op[0] = make_float4(o[0], o[1], o[2], o[3]);
  op[1] = make_float4(o[4], o[5], o[6], o[7]);
}

extern "C" void kernel_launch(void* const* d_in, const int* in_sizes, int n_in,
                              void* d_out, int out_size, void* d_ws, size_t ws_size,
                              hipStream_t stream) {
  const float* x  = (const float*)d_in[0];
  const float* cb = (const float*)d_in[1];

  float* out     = (float*)d_out;
  float* outQ    = out;
  float* outIdx  = out + (size_t)NROWS * DD;        // 8388608
  float* tail    = outIdx + (size_t)NROWS * QQ;     // expired[8], losses[8]
  float* outLoss = tail + QQ;

  _Float16* Hs = (_Float16*)outQ;                   // fp16[8192*512]
  _Float16* Ms = (_Float16*)(outQ + 2097152);
  float*    c2g = outQ + 4194304;

  const size_t shmem = 131072 + 4096 + 2048 + 2048 + 256;  // 139520 B
  (void)hipFuncSetAttribute((const void*)rvq_mfma,
                            hipFuncAttributeMaxDynamicSharedMemorySize,
                            (int)shmem);

  tail_init<<<1, 64, 0, stream>>>(tail);
  prep_kernel<<<(QQ * KK) / 4, 256, 0, stream>>>(cb, Hs, Ms, c2g);
  rvq_mfma<<<NBLK, NT, shmem, stream>>>(x, cb, Hs, Ms, c2g, outIdx, outLoss);
  recon_kernel<<<NROWS / 4, 256, 0, stream>>>(cb, outIdx, outQ);
  tail_fin<<<1, 64, 0, stream>>>(outLoss);
}

// Round 7
// 730.058 us; speedup vs baseline: 6.2354x; 1.0921x over previous
//
#include <hip/hip_runtime.h>

// ResidualVQ on MI355X — split-fp16 MFMA, round 6: latency-targeted.
// x [8,2048,512] f32, codebooks [8,1024,512] f32.
// d_out (float*): quantized [8388608], indices [131072], expired [8], losses [8].
//
// r = h + m  (h=fp16(r), m=fp16(r-h), UNSCALED -> all three MFMA products
// hH + hM + mH accumulate into ONE fp32 acc; dropped mM ~1e-6).
// Distances compared as c2 - 2*dot (r2 is per-row constant).
// Round-6: single merged accumulator (frees 64 VGPR), register
// double-buffered B prefetch (covers L2 latency), packed B layout
// [code][kc][h(32)|m(32)], update-phase codeword loads hoisted, one
// barrier/stage removed.
// (Round-7 resubmit: round 6 never ran — GPU acquisition timeout.)

typedef _Float16 half8 __attribute__((ext_vector_type(8)));
typedef float f32x4 __attribute__((ext_vector_type(4)));

constexpr int DD = 512;
constexpr int KK = 1024;
constexpr int QQ = 8;
constexpr int NROWS = 16384;
constexpr int BM = 64;
constexpr int NBLK = NROWS / BM;   // 256
constexpr int NT = 512;            // 8 waves

__global__ void tail_init(float* __restrict__ tail) {
  if (threadIdx.x < 16) tail[threadIdx.x] = 0.0f;
}
__global__ void tail_fin(float* __restrict__ loss) {
  if (threadIdx.x < QQ) loss[threadIdx.x] *= (1.0f / 8388608.0f);
}

// ---- B-split + c2 precompute. Packed layout per code (1024 halfs):
//      [kc(16)][h(32 halfs) | m(32 halfs)],  kc = k/32.
__global__ __launch_bounds__(256) void prep_kernel(
    const float* __restrict__ cb, _Float16* __restrict__ Bpk,
    float* __restrict__ c2g) {
  const int code = blockIdx.x * 4 + (threadIdx.x >> 6);   // 0..8191
  const int lane = threadIdx.x & 63;
  const float4* p = reinterpret_cast<const float4*>(cb + (size_t)code * DD + lane * 8);
  float4 a = p[0], b = p[1];
  float v[8] = {a.x,a.y,a.z,a.w,b.x,b.y,b.z,b.w};
  half8 h, m;
  float s = 0.f;
  #pragma unroll
  for (int i = 0; i < 8; ++i) {
    _Float16 hi = (_Float16)v[i];
    h[i] = hi;
    m[i] = (_Float16)(v[i] - (float)hi);   // unscaled low split
    s += v[i] * v[i];
  }
  // lane covers k = lane*8 .. lane*8+7  ->  kc = lane>>2, pos = (lane&3)*8
  _Float16* dst = Bpk + (size_t)code * 1024 + (lane >> 2) * 64 + (lane & 3) * 8;
  *reinterpret_cast<half8*>(dst) = h;
  *reinterpret_cast<half8*>(dst + 32) = m;
  #pragma unroll
  for (int o = 32; o > 0; o >>= 1) s += __shfl_down(s, o, 64);
  if (lane == 0) c2g[code] = s;
}

// ---- Main fused 8-stage kernel: writes indices + loss only ----
__global__ __launch_bounds__(NT, 2) void rvq_mfma(
    const float* __restrict__ x, const float* __restrict__ cb,
    const _Float16* __restrict__ Bpk, const float* __restrict__ c2g,
    float* __restrict__ outIdx, float* __restrict__ outLoss) {
  extern __shared__ char smem[];
  // ash: [2 splits][64 rows][512 k] fp16, XOR-swizzled: 131072 B
  char* ash = smem;
  float* c2s = reinterpret_cast<float*>(smem + 131072);   // 1024 f
  float* bD  = c2s + KK;                                  // 512 f
  int*   bI  = reinterpret_cast<int*>(bD + NT);           // 512 i
  int*   fI  = bI + NT;                                   // 64 i

  const int tid  = threadIdx.x;
  const int lane = tid & 63;
  const int wv   = tid >> 6;
  const int lq   = lane >> 4;          // k-quarter within MFMA fragment
  const int cl   = lane & 15;          // col/row-within-tile lane part
  const int rowBase = blockIdx.x * BM;
  const int row = tid >> 3;            // 0..63 (staging/update ownership)
  const int seg = tid & 7;             // 64-k chunk

  auto aAddr = [&](int split, int r, int k) -> char* {
    return ash + split * 65536 + (((r << 10) + (k << 1)) ^ ((r & 7) << 4));
  };

  // ---- Prologue: residual = x -> (h,m) fp16 splits in LDS ----
  {
    const float4* xp = reinterpret_cast<const float4*>(
        x + (size_t)(rowBase + row) * DD + seg * 64);
    #pragma unroll
    for (int g = 0; g < 8; ++g) {
      float4 a = xp[2*g], b = xp[2*g+1];
      float v[8] = {a.x,a.y,a.z,a.w,b.x,b.y,b.z,b.w};
      half8 h, m;
      #pragma unroll
      for (int i = 0; i < 8; ++i) {
        _Float16 hi = (_Float16)v[i];
        h[i] = hi;
        m[i] = (_Float16)(v[i] - (float)hi);
      }
      const int k0 = seg * 64 + g * 8;
      *reinterpret_cast<half8*>(aAddr(0, row, k0)) = h;
      *reinterpret_cast<half8*>(aAddr(1, row, k0)) = m;
    }
  }

  for (int q = 0; q < QQ; ++q) {
    // stage c2 -> LDS (NT=512 threads cover KK=1024 in two strides)
    c2s[tid]       = c2g[q * KK + tid];
    c2s[tid + 512] = c2g[q * KK + tid + 512];
    __syncthreads();   // also orders prev-stage LDS A-writes vs GEMM reads

    const _Float16* Bq = Bpk + (size_t)q * KK * 1024;

    float bestD[16];
    int   bestC[16];
    #pragma unroll
    for (int s = 0; s < 16; ++s) { bestD[s] = 3.0e38f; bestC[s] = 0; }

    #pragma unroll 1
    for (int pass = 0; pass < 2; ++pass) {
      const int colTile = wv * 128 + pass * 64;   // + ct*16 + cl

      f32x4 acc[4][4];
      #pragma unroll
      for (int ct = 0; ct < 4; ++ct)
        #pragma unroll
        for (int mt = 0; mt < 4; ++mt) acc[ct][mt] = (f32x4){0.f,0.f,0.f,0.f};

      auto loadB = [&](int kc, half8 (&bh)[4], half8 (&bm)[4]) {
        #pragma unroll
        for (int ct = 0; ct < 4; ++ct) {
          const _Float16* bp = Bq + (size_t)(colTile + ct*16 + cl) * 1024
                               + kc * 64 + lq * 8;
          bh[ct] = *reinterpret_cast<const half8*>(bp);
          bm[ct] = *reinterpret_cast<const half8*>(bp + 32);
        }
      };
      auto loadA = [&](int kc, half8 (&ah)[4], half8 (&am)[4]) {
        const int k0 = kc * 32 + lq * 8;
        #pragma unroll
        for (int mt = 0; mt < 4; ++mt) {
          const int r = mt * 16 + cl;
          ah[mt] = *reinterpret_cast<const half8*>(aAddr(0, r, k0));
          am[mt] = *reinterpret_cast<const half8*>(aAddr(1, r, k0));
        }
      };
      auto mm = [&](half8 (&ah)[4], half8 (&am)[4],
                    half8 (&bh)[4], half8 (&bm)[4]) {
        #pragma unroll
        for (int ct = 0; ct < 4; ++ct)
          #pragma unroll
          for (int mt = 0; mt < 4; ++mt) {
            acc[ct][mt] = __builtin_amdgcn_mfma_f32_16x16x32_f16(ah[mt], bh[ct], acc[ct][mt], 0, 0, 0);
            acc[ct][mt] = __builtin_amdgcn_mfma_f32_16x16x32_f16(ah[mt], bm[ct], acc[ct][mt], 0, 0, 0);
            acc[ct][mt] = __builtin_amdgcn_mfma_f32_16x16x32_f16(am[mt], bh[ct], acc[ct][mt], 0, 0, 0);
          }
      };

      half8 bh0[4], bm0[4], bh1[4], bm1[4], ah[4], am[4];
      loadB(0, bh0, bm0);                     // prologue prefetch
      #pragma unroll 1
      for (int kc2 = 0; kc2 < 8; ++kc2) {
        const int kc = kc2 * 2;
        loadB(kc + 1, bh1, bm1);              // prefetch next while computing
        loadA(kc, ah, am);
        mm(ah, am, bh0, bm0);
        loadB(kc + 2 < 16 ? kc + 2 : 15, bh0, bm0);  // tail clamp (harmless)
        loadA(kc + 1, ah, am);
        mm(ah, am, bh1, bm1);
      }

      // distances for this pass (cols ascending: pass-major, ct-minor)
      #pragma unroll
      for (int ct = 0; ct < 4; ++ct) {
        const int col = colTile + ct * 16 + cl;
        const float c2v = c2s[col];
        #pragma unroll
        for (int mt = 0; mt < 4; ++mt) {
          #pragma unroll
          for (int r = 0; r < 4; ++r) {
            const float d = c2v - 2.0f * acc[ct][mt][r];
            const int s = mt * 4 + r;
            if (d < bestD[s]) { bestD[s] = d; bestC[s] = col; }
          }
        }
      }
    }

    // cross-lane argmin within 16-lane col groups (tie -> lower col)
    #pragma unroll
    for (int s = 0; s < 16; ++s) {
      #pragma unroll
      for (int xm = 1; xm <= 8; xm <<= 1) {
        const float od = __shfl_xor(bestD[s], xm, 64);
        const int   oc = __shfl_xor(bestC[s], xm, 64);
        if (od < bestD[s] || (od == bestD[s] && oc < bestC[s])) {
          bestD[s] = od; bestC[s] = oc;
        }
      }
    }
    if ((lane & 15) == 0) {
      #pragma unroll
      for (int s = 0; s < 16; ++s) {
        const int rl = (s >> 2) * 16 + lq * 4 + (s & 3);
        bD[wv * 64 + rl] = bestD[s];
        bI[wv * 64 + rl] = bestC[s];
      }
    }
    __syncthreads();
    // cross-wave (ascending col ranges, strict < keeps first occurrence)
    if (tid < BM) {
      float best = bD[tid];
      int bi = bI[tid];
      #pragma unroll
      for (int w = 1; w < 8; ++w) {
        const float dw = bD[w * 64 + tid];
        if (dw < best) { best = dw; bi = bI[w * 64 + tid]; }
      }
      fI[tid] = bi;
      outIdx[(size_t)(rowBase + tid) * QQ + q] = (float)bi;
    }
    __syncthreads();

    // ---- Update: r -= codebook[idx]; re-split; loss += r_new^2 ----
    {
      const int myI = fI[row];
      const float4* cp = reinterpret_cast<const float4*>(
          cb + ((size_t)q * KK + myI) * DD + seg * 64);
      float4 cv[16];
      #pragma unroll
      for (int j = 0; j < 16; ++j) cv[j] = cp[j];   // hoist all loads
      float s2 = 0.f;
      #pragma unroll
      for (int g = 0; g < 8; ++g) {
        const int k0 = seg * 64 + g * 8;
        half8 h = *reinterpret_cast<const half8*>(aAddr(0, row, k0));
        half8 m = *reinterpret_cast<const half8*>(aAddr(1, row, k0));
        float4 ca = cv[2*g], cb4 = cv[2*g+1];
        float c[8] = {ca.x,ca.y,ca.z,ca.w,cb4.x,cb4.y,cb4.z,cb4.w};
        half8 nh, nm;
        #pragma unroll
        for (int i = 0; i < 8; ++i) {
          const float r0 = (float)h[i] + (float)m[i];
          const float rn = r0 - c[i];
          s2 += rn * rn;
          _Float16 hi = (_Float16)rn;
          nh[i] = hi;
          nm[i] = (_Float16)(rn - (float)hi);
        }
        *reinterpret_cast<half8*>(aAddr(0, row, k0)) = nh;
        *reinterpret_cast<half8*>(aAddr(1, row, k0)) = nm;
      }
      #pragma unroll
      for (int o = 32; o > 0; o >>= 1) s2 += __shfl_down(s2, o, 64);
      if (lane == 0) atomicAdd(outLoss + q, s2);
    }
    // no trailing barrier: next stage's c2 barrier orders these LDS writes
  }
}

// ---- Reconstruction: quantized_out = sum_q codebook[q][idx_q] (np order) ----
__global__ __launch_bounds__(256) void recon_kernel(
    const float* __restrict__ cb, const float* __restrict__ outIdx,
    float* __restrict__ outQ) {
  const int row = blockIdx.x * 4 + (threadIdx.x >> 6);
  const int lane = threadIdx.x & 63;
  const int d0 = lane * 8;
  float o[8] = {0,0,0,0,0,0,0,0};
  #pragma unroll
  for (int q = 0; q < QQ; ++q) {
    const int idx = (int)outIdx[(size_t)row * QQ + q];
    const float4* cp = reinterpret_cast<const float4*>(
        cb + ((size_t)q * KK + idx) * DD + d0);
    float4 a = cp[0], b = cp[1];
    o[0] += a.x; o[1] += a.y; o[2] += a.z; o[3] += a.w;
    o[4] += b.x; o[5] += b.y; o[6] += b.z; o[7] += b.w;
  }
  float4* op = reinterpret_cast<float4*>(outQ + (size_t)row * DD + d0);
  op[0] = make_float4(o[0], o[1], o[2], o[3]);
  op[1] = make_float4(o[4], o[5], o[6], o[7]);
}

extern "C" void kernel_launch(void* const* d_in, const int* in_sizes, int n_in,
                              void* d_out, int out_size, void* d_ws, size_t ws_size,
                              hipStream_t stream) {
  const float* x  = (const float*)d_in[0];
  const float* cb = (const float*)d_in[1];

  float* out     = (float*)d_out;
  float* outQ    = out;
  float* outIdx  = out + (size_t)NROWS * DD;        // 8388608
  float* tail    = outIdx + (size_t)NROWS * QQ;     // expired[8], losses[8]
  float* outLoss = tail + QQ;

  // scratch inside outQ region (recon overwrites it at the end):
  _Float16* Bpk = (_Float16*)outQ;                  // 8192 codes * 1024 halfs
  float*    c2g = outQ + 4300800;                   // past Bpk (4.2M floats)

  const size_t shmem = 131072 + 4096 + 2048 + 2048 + 256;  // 139520 B
  (void)hipFuncSetAttribute((const void*)rvq_mfma,
                            hipFuncAttributeMaxDynamicSharedMemorySize,
                            (int)shmem);

  tail_init<<<1, 64, 0, stream>>>(tail);
  prep_kernel<<<(QQ * KK) / 4, 256, 0, stream>>>(cb, Bpk, c2g);
  rvq_mfma<<<NBLK, NT, shmem, stream>>>(x, cb, Bpk, c2g, outIdx, outLoss);
  recon_kernel<<<NROWS / 4, 256, 0, stream>>>(cb, outIdx, outQ);
  tail_fin<<<1, 64, 0, stream>>>(outLoss);
}